// Round 2
// baseline (619.234 us; speedup 1.0000x reference)
//
#include <hip/hip_runtime.h>
#include <hip/hip_bf16.h>
#include <cstddef>

// Problem constants (from reference setup_inputs)
#define B_DIM 4096
#define D_DIM 2048
#define S_DIM 2048
#define KNOTS 20
#define T_MAX 5.0f

// Tiling for fused kernel
#define BM 64
#define BN 64
#define BK 16
#define BTILES 2                 // b-tiles per block -> chunk of 128 rows
#define NCHUNK (B_DIM / (BM * BTILES))   // 32 B-chunks

// ---------------------------------------------------------------------------
// Kernel 1: column sum-of-squares of A (norm^2 per slice). grid (32, 8) x 256
// ---------------------------------------------------------------------------
__global__ __launch_bounds__(256) void knorm(const float* __restrict__ A,
                                             float* __restrict__ norm2) {
    const int tid = threadIdx.x;
    const int j = tid & 63;          // column lane within 64-col block
    const int g = tid >> 6;          // d-subgroup 0..3
    const int s = blockIdx.x * 64 + j;
    const int d0 = blockIdx.y * 256 + g * 64;
    float acc = 0.f;
#pragma unroll 8
    for (int i = 0; i < 64; ++i) {
        float v = A[(size_t)(d0 + i) * S_DIM + s];
        acc = fmaf(v, v, acc);
    }
    __shared__ float red[256];
    red[tid] = acc;
    __syncthreads();
    if (tid < 64) {
        float v = red[tid] + red[tid + 64] + red[tid + 128] + red[tid + 192];
        atomicAdd(&norm2[s], v);
    }
}

// ---------------------------------------------------------------------------
// Kernel 2: fused GEMM (proj = E @ A, scaled by 1/norm) + characteristic-fn
// partial sums over this block's B-chunk. grid (S/BN=32, NCHUNK=32) x 256.
// ATOMIC=false: partials layout P[chunk][kk(0..18)][c(re/im)][s] (store)
// ATOMIC=true : partials layout P[kk][c][s] (atomicAdd, chunk dim folded)
// ---------------------------------------------------------------------------
template <bool ATOMIC>
__global__ __launch_bounds__(256, 2) void kfused(const float* __restrict__ E,
                                                 const float* __restrict__ A,
                                                 const float* __restrict__ norm2,
                                                 float* __restrict__ partials) {
    const int sblk = blockIdx.x;
    const int bchunk = blockIdx.y;
    const int s0 = sblk * BN;
    const int tid = threadIdx.x;
    const int tx = tid & 15;         // micro-tile col group
    const int ty = tid >> 4;         // micro-tile row group
    const int j = tid & 63;          // CF: s-lane
    const int g = tid >> 6;          // CF: b-subgroup 0..3

    __shared__ float As[BK][BM + 4];     // E-tile, transposed: As[k][m]
    __shared__ float Bs[BK][BN + 4];     // A-tile: Bs[k][n]
    __shared__ float Pj[BM][BN + 4];     // proj staging / reduction scratch

    const float invn = rsqrtf(norm2[s0 + j]);
    const float DTSTEP = T_MAX / (float)(KNOTS - 1);

    float accRe[KNOTS - 1], accIm[KNOTS - 1];
#pragma unroll
    for (int k = 0; k < KNOTS - 1; ++k) { accRe[k] = 0.f; accIm[k] = 0.f; }

    const int lrow = tid >> 2, lq = tid & 3;   // E-tile load: 64 rows x 4 quads
    const int brow = tid >> 4, bq = tid & 15;  // A-tile load: 16 rows x 16 quads

    for (int bt = 0; bt < BTILES; ++bt) {
        const int b0 = (bchunk * BTILES + bt) * BM;
        float acc[4][4];
#pragma unroll
        for (int i = 0; i < 4; ++i)
#pragma unroll
            for (int jj = 0; jj < 4; ++jj) acc[i][jj] = 0.f;

        // register prefetch of first tile
        float4 ev = *(const float4*)&E[(size_t)(b0 + lrow) * D_DIM + 0 + lq * 4];
        float4 av = *(const float4*)&A[(size_t)(0 + brow) * S_DIM + s0 + bq * 4];

        for (int kt = 0; kt < D_DIM; kt += BK) {
            __syncthreads();   // previous tile's LDS reads done
            As[lq * 4 + 0][lrow] = ev.x;
            As[lq * 4 + 1][lrow] = ev.y;
            As[lq * 4 + 2][lrow] = ev.z;
            As[lq * 4 + 3][lrow] = ev.w;
            *(float4*)&Bs[brow][bq * 4] = av;
            __syncthreads();
            // prefetch next tile while computing this one
            if (kt + BK < D_DIM) {
                ev = *(const float4*)&E[(size_t)(b0 + lrow) * D_DIM + (kt + BK) + lq * 4];
                av = *(const float4*)&A[(size_t)(kt + BK + brow) * S_DIM + s0 + bq * 4];
            }
#pragma unroll
            for (int kk = 0; kk < BK; ++kk) {
                float4 a = *(const float4*)&As[kk][ty * 4];
                float4 b = *(const float4*)&Bs[kk][tx * 4];
                acc[0][0] = fmaf(a.x, b.x, acc[0][0]);
                acc[0][1] = fmaf(a.x, b.y, acc[0][1]);
                acc[0][2] = fmaf(a.x, b.z, acc[0][2]);
                acc[0][3] = fmaf(a.x, b.w, acc[0][3]);
                acc[1][0] = fmaf(a.y, b.x, acc[1][0]);
                acc[1][1] = fmaf(a.y, b.y, acc[1][1]);
                acc[1][2] = fmaf(a.y, b.z, acc[1][2]);
                acc[1][3] = fmaf(a.y, b.w, acc[1][3]);
                acc[2][0] = fmaf(a.z, b.x, acc[2][0]);
                acc[2][1] = fmaf(a.z, b.y, acc[2][1]);
                acc[2][2] = fmaf(a.z, b.z, acc[2][2]);
                acc[2][3] = fmaf(a.z, b.w, acc[2][3]);
                acc[3][0] = fmaf(a.w, b.x, acc[3][0]);
                acc[3][1] = fmaf(a.w, b.y, acc[3][1]);
                acc[3][2] = fmaf(a.w, b.z, acc[3][2]);
                acc[3][3] = fmaf(a.w, b.w, acc[3][3]);
            }
        }
        // stage proj tile to LDS for thread remap (rows->b, cols->s)
        __syncthreads();
#pragma unroll
        for (int i = 0; i < 4; ++i)
            *(float4*)&Pj[ty * 4 + i][tx * 4] =
                make_float4(acc[i][0], acc[i][1], acc[i][2], acc[i][3]);
        __syncthreads();

        // CF phase: 4 threads per s-column, 16 b-rows each.
        // t_k = k*DT; rotate (c,s) by theta = p*DT each step; skip k=0 (err==0).
#pragma unroll 2
        for (int bl = g * 16; bl < g * 16 + 16; ++bl) {
            float p = Pj[bl][j] * invn;
            float sn, cs;
            __sincosf(p * DTSTEP, &sn, &cs);
            float c = cs, s = sn;
            accRe[0] += c; accIm[0] += s;
#pragma unroll
            for (int kk = 1; kk < KNOTS - 1; ++kk) {
                float cn = fmaf(c, cs, -s * sn);
                s = fmaf(s, cs, c * sn);
                c = cn;
                accRe[kk] += c; accIm[kk] += s;
            }
        }
    }

    // reduce the 4 b-subgroups per s-column through LDS (reuse Pj: 2432 floats)
    __syncthreads();
    float* red = &Pj[0][0];
    if (g == 0) {
#pragma unroll
        for (int kk = 0; kk < KNOTS - 1; ++kk) {
            red[(kk * 2 + 0) * 64 + j] = accRe[kk];
            red[(kk * 2 + 1) * 64 + j] = accIm[kk];
        }
    }
    __syncthreads();
    for (int gg = 1; gg < 4; ++gg) {
        if (g == gg) {
#pragma unroll
            for (int kk = 0; kk < KNOTS - 1; ++kk) {
                red[(kk * 2 + 0) * 64 + j] += accRe[kk];
                red[(kk * 2 + 1) * 64 + j] += accIm[kk];
            }
        }
        __syncthreads();
    }

    // write this block's partial sums (coalesced per 64-lane row)
    if (tid < 64) {
        for (int kk = 0; kk < KNOTS - 1; ++kk) {
            for (int c = 0; c < 2; ++c) {
                const int row = ATOMIC ? kk : (bchunk * (KNOTS - 1) + kk);
                float* dst = &partials[(size_t)(row * 2 + c) * S_DIM + s0 + tid];
                const float v = red[(kk * 2 + c) * 64 + tid];
                if (ATOMIC) atomicAdd(dst, v);
                else        *dst = v;
            }
        }
    }
}

// ---------------------------------------------------------------------------
// Kernel 3: finalize. One thread per (s, kk) pair; sums chunk partials,
// computes weighted err, block-reduce, atomicAdd scalar. grid 152 x 256.
// ---------------------------------------------------------------------------
template <int NCH>
__global__ __launch_bounds__(256) void kfinal(const float* __restrict__ partials,
                                              const float* __restrict__ phi,
                                              const float* __restrict__ wts,
                                              float* __restrict__ out) {
    const int idx = blockIdx.x * 256 + threadIdx.x;
    const int kk = idx >> 11;        // / S_DIM
    const int s = idx & (S_DIM - 1);
    const float invB = 1.0f / (float)B_DIM;

    float re = 0.f, im = 0.f;
    for (int ch = 0; ch < NCH; ++ch) {
        re += partials[(size_t)((ch * (KNOTS - 1) + kk) * 2 + 0) * S_DIM + s];
        im += partials[(size_t)((ch * (KNOTS - 1) + kk) * 2 + 1) * S_DIM + s];
    }
    re = re * invB - phi[kk + 1];
    im *= invB;
    float local = wts[kk + 1] * fmaf(re, re, im * im);

    __shared__ float sred[256];
    sred[threadIdx.x] = local;
    __syncthreads();
    for (int off = 128; off > 0; off >>= 1) {
        if (threadIdx.x < off) sred[threadIdx.x] += sred[threadIdx.x + off];
        __syncthreads();
    }
    if (threadIdx.x == 0) {
        const float scale = (float)D_DIM / (float)S_DIM;   // statistic*D, mean over S
        atomicAdd(out, sred[0] * scale);
    }
}

// ---------------------------------------------------------------------------
extern "C" void kernel_launch(void* const* d_in, const int* in_sizes, int n_in,
                              void* d_out, int out_size, void* d_ws, size_t ws_size,
                              hipStream_t stream) {
    const float* E   = (const float*)d_in[0];   // embeddings [B, D]
    const float* A   = (const float*)d_in[1];   // projection [D, S]
    const float* phi = (const float*)d_in[3];   // [K]
    const float* wts = (const float*)d_in[4];   // [K] (= w * phi)
    float* out = (float*)d_out;

    float* ws_f = (float*)d_ws;
    float* norm2 = ws_f;                         // S floats
    float* partials = ws_f + S_DIM;              // layout depends on path

    const size_t part_full = (size_t)NCHUNK * (KNOTS - 1) * 2 * S_DIM;  // ~10 MB
    const size_t part_atom = (size_t)(KNOTS - 1) * 2 * S_DIM;           // ~312 KB
    // ws_size is fixed for the session -> branch is identical every call
    const bool big_ws = ws_size >= (S_DIM + part_full) * sizeof(float);

    hipMemsetAsync(norm2, 0, S_DIM * sizeof(float), stream);
    hipMemsetAsync(out, 0, sizeof(float), stream);

    knorm<<<dim3(S_DIM / 64, D_DIM / 256), 256, 0, stream>>>(A, norm2);

    if (big_ws) {
        kfused<false><<<dim3(S_DIM / BN, NCHUNK), 256, 0, stream>>>(E, A, norm2, partials);
        kfinal<NCHUNK><<<dim3((KNOTS - 1) * S_DIM / 256), 256, 0, stream>>>(partials, phi, wts, out);
    } else {
        hipMemsetAsync(partials, 0, part_atom * sizeof(float), stream);
        kfused<true><<<dim3(S_DIM / BN, NCHUNK), 256, 0, stream>>>(E, A, norm2, partials);
        kfinal<1><<<dim3((KNOTS - 1) * S_DIM / 256), 256, 0, stream>>>(partials, phi, wts, out);
    }
}

// Round 3
// 252.858 us; speedup vs baseline: 2.4489x; 2.4489x over previous
//
#include <hip/hip_runtime.h>
#include <hip/hip_bf16.h>
#include <cstddef>
#include <cstdint>

// Problem constants
#define B_DIM 4096
#define D_DIM 2048
#define S_DIM 2048
#define KNOTS 20
#define T_MAX 5.0f

typedef unsigned short ushort_t;
typedef __attribute__((ext_vector_type(8))) short short8_t;    // 8 bf16 (4 VGPR)
typedef __attribute__((ext_vector_type(4))) float f32x4;
typedef __attribute__((ext_vector_type(8))) unsigned short ushort8_t;
typedef __attribute__((ext_vector_type(4))) unsigned short ushort4_t;

// ---- bf16 helpers (bit-level, avoids __hip_bfloat16 ABI differences) ----
__device__ __forceinline__ ushort_t f2bf(float f) {
    unsigned u = __float_as_uint(f);
    u += 0x7FFFu + ((u >> 16) & 1u);     // round-to-nearest-even
    return (ushort_t)(u >> 16);
}
__device__ __forceinline__ float bf2f(ushort_t h) {
    return __uint_as_float(((unsigned)h) << 16);
}

// ---- async global->LDS 16B ----
__device__ __forceinline__ void gload16(const void* g, void* l) {
    __builtin_amdgcn_global_load_lds(
        (const __attribute__((address_space(1))) unsigned int*)g,
        (__attribute__((address_space(3))) unsigned int*)l, 16, 0, 0);
}

// ===========================================================================
// Kernel 1: column sum-of-squares of A. grid (32, 8) x 256
// ===========================================================================
__global__ __launch_bounds__(256) void knorm(const float* __restrict__ A,
                                             float* __restrict__ norm2) {
    const int tid = threadIdx.x;
    const int j = tid & 63;
    const int g = tid >> 6;
    const int s = blockIdx.x * 64 + j;
    const int d0 = blockIdx.y * 256 + g * 64;
    float acc = 0.f;
#pragma unroll 8
    for (int i = 0; i < 64; ++i) {
        float v = A[(size_t)(d0 + i) * S_DIM + s];
        acc = fmaf(v, v, acc);
    }
    __shared__ float red[256];
    red[tid] = acc;
    __syncthreads();
    if (tid < 64) {
        float v = red[tid] + red[tid + 64] + red[tid + 128] + red[tid + 192];
        atomicAdd(&norm2[s], v);
    }
}

// ===========================================================================
// Kernel 2a: E [B][D] fp32 -> Eh, El [B][D] bf16 (hi/lo split). 4096 x 256
// ===========================================================================
__global__ __launch_bounds__(256) void kconvE(const float* __restrict__ E,
                                              ushort_t* __restrict__ Eh,
                                              ushort_t* __restrict__ El) {
    const size_t i = ((size_t)blockIdx.x * 256 + threadIdx.x) * 8;
    float4 v0 = *(const float4*)&E[i];
    float4 v1 = *(const float4*)&E[i + 4];
    float f[8] = {v0.x, v0.y, v0.z, v0.w, v1.x, v1.y, v1.z, v1.w};
    ushort8_t h, l;
#pragma unroll
    for (int j = 0; j < 8; ++j) {
        ushort_t hb = f2bf(f[j]);
        h[j] = hb;
        l[j] = f2bf(f[j] - bf2f(hb));
    }
    *(ushort8_t*)&Eh[i] = h;
    *(ushort8_t*)&El[i] = l;
}

// ===========================================================================
// Kernel 2b: A [D][S] fp32 -> Aht, Alt [S][D] bf16 (normalized, transposed).
// grid (D/64=32, S/64=32) x 256
// ===========================================================================
__global__ __launch_bounds__(256) void kconvA(const float* __restrict__ A,
                                              const float* __restrict__ norm2,
                                              ushort_t* __restrict__ Aht,
                                              ushort_t* __restrict__ Alt) {
    __shared__ float T[64][69];
    const int t = threadIdx.x;
    const int d0 = blockIdx.x * 64, s0 = blockIdx.y * 64;
    const int dl = t >> 2, c4 = t & 3;
#pragma unroll
    for (int q = 0; q < 4; ++q) {
        int sc = c4 * 16 + q * 4;
        float4 v = *(const float4*)&A[(size_t)(d0 + dl) * S_DIM + s0 + sc];
        T[dl][sc + 0] = v.x; T[dl][sc + 1] = v.y;
        T[dl][sc + 2] = v.z; T[dl][sc + 3] = v.w;
    }
    __syncthreads();
#pragma unroll
    for (int p = 0; p < 4; ++p) {
        int sl = p * 16 + (t >> 4);
        float invn = rsqrtf(norm2[s0 + sl]);
        int dof = (t & 15) * 4;
        ushort4_t h, l;
#pragma unroll
        for (int i = 0; i < 4; ++i) {
            float x = T[dof + i][sl] * invn;
            ushort_t hb = f2bf(x);
            h[i] = hb;
            l[i] = f2bf(x - bf2f(hb));
        }
        *(ushort4_t*)&Aht[(size_t)(s0 + sl) * D_DIM + d0 + dof] = h;
        *(ushort4_t*)&Alt[(size_t)(s0 + sl) * D_DIM + d0 + dof] = l;
    }
}

// ===========================================================================
// Kernel 3: split-bf16 MFMA GEMM (proj = E @ A_n) fused with CF epilogue.
// grid (S/128=16, B/128=32) x 256 (4 waves, 2x2 of 64x64 wave tiles).
// partials layout: P[bchunk=32][k=19][c=2][s=2048]
// ===========================================================================
__global__ __launch_bounds__(256, 2) void kmain(const ushort_t* __restrict__ Eh,
                                                const ushort_t* __restrict__ El,
                                                const ushort_t* __restrict__ Aht,
                                                const ushort_t* __restrict__ Alt,
                                                float* __restrict__ partials) {
    __shared__ __align__(16) char smem[39936];
    ushort_t* Ehs = (ushort_t*)smem;          // [128][32] bf16 = 8KB
    ushort_t* Els = Ehs + 4096;
    ushort_t* Ahs = Els + 4096;               // [128 s][32 d]
    ushort_t* Als = Ahs + 4096;
    float* cf = (float*)smem;                 // CF: [p=2][g=2][64][38] = 38.9KB

    const int tid = threadIdx.x;
    const int lane = tid & 63, wid = tid >> 6;
    const int wm = (wid & 1) * 64, wn = (wid >> 1) * 64;
    const int s0 = blockIdx.x * 128, b0 = blockIdx.y * 128;

    f32x4 acc[4][4];
#pragma unroll
    for (int mt = 0; mt < 4; ++mt)
#pragma unroll
        for (int nt = 0; nt < 4; ++nt)
            acc[mt][nt] = (f32x4){0.f, 0.f, 0.f, 0.f};

    const int r_ld = tid >> 2;      // 0..63
    const int c_ld = tid & 3;       // 16B chunk within 64B row
    const int lds_lin = tid * 8;    // ushort offset = tid*16B
    const int kc = (lane >> 4) * 8; // frag k-chunk

    for (int kt = 0; kt < D_DIM; kt += 32) {
        // stage 4 tiles (2 statements each: rows 0-63, 64-127)
#pragma unroll
        for (int st = 0; st < 2; ++st) {
            const int r = st * 64 + r_ld;
            const size_t eoff = (size_t)(b0 + r) * D_DIM + kt + c_ld * 8;
            const size_t aoff = (size_t)(s0 + r) * D_DIM + kt + c_ld * 8;
            const int ldo = st * 2048 + lds_lin;
            gload16(Eh + eoff, Ehs + ldo);
            gload16(El + eoff, Els + ldo);
            gload16(Aht + aoff, Ahs + ldo);
            gload16(Alt + aoff, Als + ldo);
        }
        __syncthreads();

        short8_t ah[4], al[4], bh[4], bl[4];
#pragma unroll
        for (int mt = 0; mt < 4; ++mt) {
            int row = wm + mt * 16 + (lane & 15);
            ah[mt] = *(const short8_t*)&Ehs[row * 32 + kc];
            al[mt] = *(const short8_t*)&Els[row * 32 + kc];
        }
#pragma unroll
        for (int nt = 0; nt < 4; ++nt) {
            int row = wn + nt * 16 + (lane & 15);
            bh[nt] = *(const short8_t*)&Ahs[row * 32 + kc];
            bl[nt] = *(const short8_t*)&Als[row * 32 + kc];
        }
#pragma unroll
        for (int mt = 0; mt < 4; ++mt)
#pragma unroll
            for (int nt = 0; nt < 4; ++nt) {
                acc[mt][nt] = __builtin_amdgcn_mfma_f32_16x16x32_bf16(ah[mt], bh[nt], acc[mt][nt], 0, 0, 0);
                acc[mt][nt] = __builtin_amdgcn_mfma_f32_16x16x32_bf16(ah[mt], bl[nt], acc[mt][nt], 0, 0, 0);
                acc[mt][nt] = __builtin_amdgcn_mfma_f32_16x16x32_bf16(al[mt], bh[nt], acc[mt][nt], 0, 0, 0);
            }
        __syncthreads();
    }

    // ---- CF epilogue on acc registers ----
    // C layout (16x16x32): col = lane&15, row = (lane>>4)*4 + reg.
    // Lane's 4 values per tile share one s column -> rotate+accumulate per lane,
    // reduce over {lane^16, lane^32}, combine m-waves through LDS.
    __syncthreads();   // GEMM LDS reads fully done before cf overwrite
    const float DT = T_MAX / (float)(KNOTS - 1);

#pragma unroll
    for (int nt = 0; nt < 4; ++nt) {
        float re[KNOTS - 1], im[KNOTS - 1];
#pragma unroll
        for (int k = 0; k < KNOTS - 1; ++k) { re[k] = 0.f; im[k] = 0.f; }
#pragma unroll
        for (int mt = 0; mt < 4; ++mt) {
            f32x4 v = acc[mt][nt];
#pragma unroll
            for (int r = 0; r < 4; ++r) {
                float p = v[r];
                float sn, cs;
                __sincosf(p * DT, &sn, &cs);
                float c = cs, s = sn;
                re[0] += c; im[0] += s;
#pragma unroll
                for (int k = 1; k < KNOTS - 1; ++k) {
                    float cn = fmaf(c, cs, -s * sn);
                    s = fmaf(s, cs, c * sn);
                    c = cn;
                    re[k] += c; im[k] += s;
                }
            }
        }
#pragma unroll
        for (int k = 0; k < KNOTS - 1; ++k) {
            re[k] += __shfl_xor(re[k], 16);
            re[k] += __shfl_xor(re[k], 32);
            im[k] += __shfl_xor(im[k], 16);
            im[k] += __shfl_xor(im[k], 32);
        }
        if (lane < 16) {
            const int sig = nt * 16 + lane;   // s within 64-col group
            float* dst = &cf[(size_t)((((wid & 1) * 2 + (wid >> 1)) * 64 + sig)) * 38];
#pragma unroll
            for (int k = 0; k < KNOTS - 1; ++k) {
                dst[2 * k]     = re[k];
                dst[2 * k + 1] = im[k];
            }
        }
    }
    __syncthreads();

    // combine the two m-parity waves and write partials (coalesced in s)
#pragma unroll
    for (int i = 0; i < KNOTS - 1; ++i) {
        const int kc2 = i * 2 + (tid >> 7);   // 0..37
        const int sl = tid & 127;
        const int g = sl >> 6, si = sl & 63;
        float v = cf[(size_t)(((0 * 2 + g) * 64 + si)) * 38 + kc2]
                + cf[(size_t)(((1 * 2 + g) * 64 + si)) * 38 + kc2];
        const int k = kc2 >> 1, c = kc2 & 1;
        partials[((size_t)(blockIdx.y * (KNOTS - 1) + k) * 2 + c) * S_DIM + s0 + sl] = v;
    }
}

// ===========================================================================
// Kernel 4: finalize. Sum chunk partials, weighted err, reduce to scalar.
// ===========================================================================
template <int NCH>
__global__ __launch_bounds__(256) void kfinal(const float* __restrict__ partials,
                                              const float* __restrict__ phi,
                                              const float* __restrict__ wts,
                                              float* __restrict__ out) {
    const int idx = blockIdx.x * 256 + threadIdx.x;
    const int kk = idx >> 11;
    const int s = idx & (S_DIM - 1);
    const float invB = 1.0f / (float)B_DIM;

    float re = 0.f, im = 0.f;
    for (int ch = 0; ch < NCH; ++ch) {
        re += partials[(size_t)((ch * (KNOTS - 1) + kk) * 2 + 0) * S_DIM + s];
        im += partials[(size_t)((ch * (KNOTS - 1) + kk) * 2 + 1) * S_DIM + s];
    }
    re = re * invB - phi[kk + 1];
    im *= invB;
    float local = wts[kk + 1] * fmaf(re, re, im * im);

    __shared__ float sred[256];
    sred[threadIdx.x] = local;
    __syncthreads();
    for (int off = 128; off > 0; off >>= 1) {
        if (threadIdx.x < off) sred[threadIdx.x] += sred[threadIdx.x + off];
        __syncthreads();
    }
    if (threadIdx.x == 0) {
        const float scale = (float)D_DIM / (float)S_DIM;
        atomicAdd(out, sred[0] * scale);
    }
}

// ===========================================================================
// Fallback (validated round-2 fp32 path) for small ws_size
// ===========================================================================
#define BM 64
#define BN 64
#define BK 16
#define BTILES 2
#define NCHUNK_F (B_DIM / (BM * BTILES))

template <bool ATOMIC>
__global__ __launch_bounds__(256, 2) void kfused_f32(const float* __restrict__ E,
                                                     const float* __restrict__ A,
                                                     const float* __restrict__ norm2,
                                                     float* __restrict__ partials) {
    const int sblk = blockIdx.x;
    const int bchunk = blockIdx.y;
    const int s0 = sblk * BN;
    const int tid = threadIdx.x;
    const int tx = tid & 15, ty = tid >> 4;
    const int j = tid & 63, g = tid >> 6;

    __shared__ float As[BK][BM + 4];
    __shared__ float Bs[BK][BN + 4];
    __shared__ float Pj[BM][BN + 4];

    const float invn = rsqrtf(norm2[s0 + j]);
    const float DTSTEP = T_MAX / (float)(KNOTS - 1);

    float accRe[KNOTS - 1], accIm[KNOTS - 1];
#pragma unroll
    for (int k = 0; k < KNOTS - 1; ++k) { accRe[k] = 0.f; accIm[k] = 0.f; }

    const int lrow = tid >> 2, lq = tid & 3;
    const int brow = tid >> 4, bq = tid & 15;

    for (int bt = 0; bt < BTILES; ++bt) {
        const int b0 = (bchunk * BTILES + bt) * BM;
        float acc[4][4];
#pragma unroll
        for (int i = 0; i < 4; ++i)
#pragma unroll
            for (int jj = 0; jj < 4; ++jj) acc[i][jj] = 0.f;

        float4 ev = *(const float4*)&E[(size_t)(b0 + lrow) * D_DIM + 0 + lq * 4];
        float4 av = *(const float4*)&A[(size_t)(0 + brow) * S_DIM + s0 + bq * 4];

        for (int kt = 0; kt < D_DIM; kt += BK) {
            __syncthreads();
            As[lq * 4 + 0][lrow] = ev.x;
            As[lq * 4 + 1][lrow] = ev.y;
            As[lq * 4 + 2][lrow] = ev.z;
            As[lq * 4 + 3][lrow] = ev.w;
            *(float4*)&Bs[brow][bq * 4] = av;
            __syncthreads();
            if (kt + BK < D_DIM) {
                ev = *(const float4*)&E[(size_t)(b0 + lrow) * D_DIM + (kt + BK) + lq * 4];
                av = *(const float4*)&A[(size_t)(kt + BK + brow) * S_DIM + s0 + bq * 4];
            }
#pragma unroll
            for (int kk = 0; kk < BK; ++kk) {
                float4 a = *(const float4*)&As[kk][ty * 4];
                float4 b = *(const float4*)&Bs[kk][tx * 4];
                acc[0][0] = fmaf(a.x, b.x, acc[0][0]);
                acc[0][1] = fmaf(a.x, b.y, acc[0][1]);
                acc[0][2] = fmaf(a.x, b.z, acc[0][2]);
                acc[0][3] = fmaf(a.x, b.w, acc[0][3]);
                acc[1][0] = fmaf(a.y, b.x, acc[1][0]);
                acc[1][1] = fmaf(a.y, b.y, acc[1][1]);
                acc[1][2] = fmaf(a.y, b.z, acc[1][2]);
                acc[1][3] = fmaf(a.y, b.w, acc[1][3]);
                acc[2][0] = fmaf(a.z, b.x, acc[2][0]);
                acc[2][1] = fmaf(a.z, b.y, acc[2][1]);
                acc[2][2] = fmaf(a.z, b.z, acc[2][2]);
                acc[2][3] = fmaf(a.z, b.w, acc[2][3]);
                acc[3][0] = fmaf(a.w, b.x, acc[3][0]);
                acc[3][1] = fmaf(a.w, b.y, acc[3][1]);
                acc[3][2] = fmaf(a.w, b.z, acc[3][2]);
                acc[3][3] = fmaf(a.w, b.w, acc[3][3]);
            }
        }
        __syncthreads();
#pragma unroll
        for (int i = 0; i < 4; ++i)
            *(float4*)&Pj[ty * 4 + i][tx * 4] =
                make_float4(acc[i][0], acc[i][1], acc[i][2], acc[i][3]);
        __syncthreads();

#pragma unroll 2
        for (int bl = g * 16; bl < g * 16 + 16; ++bl) {
            float p = Pj[bl][j] * invn;
            float sn, cs;
            __sincosf(p * DTSTEP, &sn, &cs);
            float c = cs, s = sn;
            accRe[0] += c; accIm[0] += s;
#pragma unroll
            for (int kk = 1; kk < KNOTS - 1; ++kk) {
                float cn = fmaf(c, cs, -s * sn);
                s = fmaf(s, cs, c * sn);
                c = cn;
                accRe[kk] += c; accIm[kk] += s;
            }
        }
    }

    __syncthreads();
    float* red = &Pj[0][0];
    if (g == 0) {
#pragma unroll
        for (int kk = 0; kk < KNOTS - 1; ++kk) {
            red[(kk * 2 + 0) * 64 + j] = accRe[kk];
            red[(kk * 2 + 1) * 64 + j] = accIm[kk];
        }
    }
    __syncthreads();
    for (int gg = 1; gg < 4; ++gg) {
        if (g == gg) {
#pragma unroll
            for (int kk = 0; kk < KNOTS - 1; ++kk) {
                red[(kk * 2 + 0) * 64 + j] += accRe[kk];
                red[(kk * 2 + 1) * 64 + j] += accIm[kk];
            }
        }
        __syncthreads();
    }

    if (tid < 64) {
        for (int kk = 0; kk < KNOTS - 1; ++kk) {
            for (int c = 0; c < 2; ++c) {
                const int row = ATOMIC ? kk : (bchunk * (KNOTS - 1) + kk);
                float* dst = &partials[(size_t)(row * 2 + c) * S_DIM + s0 + tid];
                const float v = red[(kk * 2 + c) * 64 + tid];
                if (ATOMIC) atomicAdd(dst, v);
                else        *dst = v;
            }
        }
    }
}

// ===========================================================================
extern "C" void kernel_launch(void* const* d_in, const int* in_sizes, int n_in,
                              void* d_out, int out_size, void* d_ws, size_t ws_size,
                              hipStream_t stream) {
    const float* E   = (const float*)d_in[0];
    const float* A   = (const float*)d_in[1];
    const float* phi = (const float*)d_in[3];
    const float* wts = (const float*)d_in[4];
    float* out = (float*)d_out;

    float* ws_f = (float*)d_ws;
    float* norm2 = ws_f;                          // 2048 floats
    float* partials = ws_f + S_DIM;               // 32*19*2*2048 floats

    const size_t part_elems = (size_t)32 * (KNOTS - 1) * 2 * S_DIM;  // 2,490,368
    ushort_t* Ehp  = (ushort_t*)(ws_f + S_DIM + part_elems);
    ushort_t* Elp  = Ehp + (size_t)B_DIM * D_DIM;
    ushort_t* Ahtp = Elp + (size_t)B_DIM * D_DIM;
    ushort_t* Altp = Ahtp + (size_t)S_DIM * D_DIM;

    const size_t need_bytes = (S_DIM + part_elems) * sizeof(float)
                            + (2 * (size_t)B_DIM * D_DIM + 2 * (size_t)S_DIM * D_DIM) * sizeof(ushort_t);

    hipMemsetAsync(norm2, 0, S_DIM * sizeof(float), stream);
    hipMemsetAsync(out, 0, sizeof(float), stream);

    knorm<<<dim3(S_DIM / 64, D_DIM / 256), 256, 0, stream>>>(A, norm2);

    if (ws_size >= need_bytes) {
        kconvE<<<dim3((unsigned)((size_t)B_DIM * D_DIM / 8 / 256)), 256, 0, stream>>>(E, Ehp, Elp);
        kconvA<<<dim3(D_DIM / 64, S_DIM / 64), 256, 0, stream>>>(A, norm2, Ahtp, Altp);
        kmain<<<dim3(S_DIM / 128, B_DIM / 128), 256, 0, stream>>>(Ehp, Elp, Ahtp, Altp, partials);
        kfinal<32><<<dim3((KNOTS - 1) * S_DIM / 256), 256, 0, stream>>>(partials, phi, wts, out);
    } else if (ws_size >= (S_DIM + part_elems) * sizeof(float)) {
        kfused_f32<false><<<dim3(S_DIM / BN, NCHUNK_F), 256, 0, stream>>>(E, A, norm2, partials);
        kfinal<NCHUNK_F><<<dim3((KNOTS - 1) * S_DIM / 256), 256, 0, stream>>>(partials, phi, wts, out);
    } else {
        hipMemsetAsync(partials, 0, (size_t)(KNOTS - 1) * 2 * S_DIM * sizeof(float), stream);
        kfused_f32<true><<<dim3(S_DIM / BN, NCHUNK_F), 256, 0, stream>>>(E, A, norm2, partials);
        kfinal<1><<<dim3((KNOTS - 1) * S_DIM / 256), 256, 0, stream>>>(partials, phi, wts, out);
    }
}

// Round 4
// 246.611 us; speedup vs baseline: 2.5110x; 1.0253x over previous
//
#include <hip/hip_runtime.h>
#include <hip/hip_bf16.h>
#include <cstddef>
#include <cstdint>

// Problem constants
#define B_DIM 4096
#define D_DIM 2048
#define S_DIM 2048
#define KNOTS 20
#define T_MAX 5.0f

typedef unsigned short ushort_t;
typedef __attribute__((ext_vector_type(8))) short short8_t;    // 8 bf16 (4 VGPR)
typedef __attribute__((ext_vector_type(4))) float f32x4;
typedef __attribute__((ext_vector_type(8))) unsigned short ushort8_t;
typedef __attribute__((ext_vector_type(4))) unsigned short ushort4_t;

// ---- bf16 helpers ----
__device__ __forceinline__ ushort_t f2bf(float f) {
    unsigned u = __float_as_uint(f);
    u += 0x7FFFu + ((u >> 16) & 1u);     // round-to-nearest-even
    return (ushort_t)(u >> 16);
}
__device__ __forceinline__ float bf2f(ushort_t h) {
    return __uint_as_float(((unsigned)h) << 16);
}

// ---- async global->LDS 16B ----
__device__ __forceinline__ void gload16(const void* g, void* l) {
    __builtin_amdgcn_global_load_lds(
        (const __attribute__((address_space(1))) unsigned int*)g,
        (__attribute__((address_space(3))) unsigned int*)l, 16, 0, 0);
}

// ===========================================================================
// Kernel 1: column sum-of-squares of A. grid (32, 8) x 256
// ===========================================================================
__global__ __launch_bounds__(256) void knorm(const float* __restrict__ A,
                                             float* __restrict__ norm2) {
    const int tid = threadIdx.x;
    const int j = tid & 63;
    const int g = tid >> 6;
    const int s = blockIdx.x * 64 + j;
    const int d0 = blockIdx.y * 256 + g * 64;
    float acc = 0.f;
#pragma unroll 8
    for (int i = 0; i < 64; ++i) {
        float v = A[(size_t)(d0 + i) * S_DIM + s];
        acc = fmaf(v, v, acc);
    }
    __shared__ float red[256];
    red[tid] = acc;
    __syncthreads();
    if (tid < 64) {
        float v = red[tid] + red[tid + 64] + red[tid + 128] + red[tid + 192];
        atomicAdd(&norm2[s], v);
    }
}

// ===========================================================================
// Kernel 2a: E [B][D] fp32 -> Eh, El [B][D] bf16 (hi/lo split). 4096 x 256
// ===========================================================================
__global__ __launch_bounds__(256) void kconvE(const float* __restrict__ E,
                                              ushort_t* __restrict__ Eh,
                                              ushort_t* __restrict__ El) {
    const size_t i = ((size_t)blockIdx.x * 256 + threadIdx.x) * 8;
    float4 v0 = *(const float4*)&E[i];
    float4 v1 = *(const float4*)&E[i + 4];
    float f[8] = {v0.x, v0.y, v0.z, v0.w, v1.x, v1.y, v1.z, v1.w};
    ushort8_t h, l;
#pragma unroll
    for (int j = 0; j < 8; ++j) {
        ushort_t hb = f2bf(f[j]);
        h[j] = hb;
        l[j] = f2bf(f[j] - bf2f(hb));
    }
    *(ushort8_t*)&Eh[i] = h;
    *(ushort8_t*)&El[i] = l;
}

// ===========================================================================
// Kernel 2b: A [D][S] fp32 -> Aht, Alt [S][D] bf16 (normalized, transposed).
// grid (D/64=32, S/64=32) x 256
// ===========================================================================
__global__ __launch_bounds__(256) void kconvA(const float* __restrict__ A,
                                              const float* __restrict__ norm2,
                                              ushort_t* __restrict__ Aht,
                                              ushort_t* __restrict__ Alt) {
    __shared__ float T[64][69];
    const int t = threadIdx.x;
    const int d0 = blockIdx.x * 64, s0 = blockIdx.y * 64;
    const int dl = t >> 2, c4 = t & 3;
#pragma unroll
    for (int q = 0; q < 4; ++q) {
        int sc = c4 * 16 + q * 4;
        float4 v = *(const float4*)&A[(size_t)(d0 + dl) * S_DIM + s0 + sc];
        T[dl][sc + 0] = v.x; T[dl][sc + 1] = v.y;
        T[dl][sc + 2] = v.z; T[dl][sc + 3] = v.w;
    }
    __syncthreads();
#pragma unroll
    for (int p = 0; p < 4; ++p) {
        int sl = p * 16 + (t >> 4);
        float invn = rsqrtf(norm2[s0 + sl]);
        int dof = (t & 15) * 4;
        ushort4_t h, l;
#pragma unroll
        for (int i = 0; i < 4; ++i) {
            float x = T[dof + i][sl] * invn;
            ushort_t hb = f2bf(x);
            h[i] = hb;
            l[i] = f2bf(x - bf2f(hb));
        }
        *(ushort4_t*)&Aht[(size_t)(s0 + sl) * D_DIM + d0 + dof] = h;
        *(ushort4_t*)&Alt[(size_t)(s0 + sl) * D_DIM + d0 + dof] = l;
    }
}

// ===========================================================================
// Kernel 3: split-bf16 MFMA GEMM + CF epilogue. 2-phase pipelined:
// LDS double-buffer, STAGE(t+1) issued BEFORE compute(t), ONE barrier/K-step.
// grid (16, 32) x 256 (4 waves), XCD-swizzled block remap.
// partials layout: P[bchunk=32][k=19][c=2][s=2048]
// ===========================================================================
__global__ __launch_bounds__(256, 2) void kmain(const ushort_t* __restrict__ Eh,
                                                const ushort_t* __restrict__ El,
                                                const ushort_t* __restrict__ Aht,
                                                const ushort_t* __restrict__ Alt,
                                                float* __restrict__ partials) {
    // dbuf: 2 x 32KB. buf p (ushort units, base p*16384):
    //   Ehs +0, Els +4096, Ahs +8192, Als +12288   (each [128 rows][32 k] bf16)
    // CF epilogue aliases the same LDS (needs 38912 B).
    __shared__ __align__(16) char smem[65536];
    float* cf = (float*)smem;

    const int tid = threadIdx.x;
    const int lane = tid & 63, wid = tid >> 6;
    const int wm = (wid & 1) * 64, wn = (wid >> 1) * 64;

    // T1: bijective XCD-aware remap (512 blocks, 512%8==0)
    const int lin = blockIdx.y * gridDim.x + blockIdx.x;       // dispatch order
    const int wg = (lin & 7) * 64 + (lin >> 3);
    const int sblk = wg & 15, bchunk = wg >> 4;
    const int s0 = sblk * 128, b0 = bchunk * 128;

    f32x4 acc[4][4];
#pragma unroll
    for (int mt = 0; mt < 4; ++mt)
#pragma unroll
        for (int nt = 0; nt < 4; ++nt)
            acc[mt][nt] = (f32x4){0.f, 0.f, 0.f, 0.f};

    const int r_ld = tid >> 2;      // 0..63
    const int c_ld = tid & 3;       // 16B chunk in 64B row
    const int lds_lin = tid * 8;    // ushort offset = tid*16B
    const int kc = (lane >> 4) * 8; // frag k-chunk

#define STAGE(P, KT)                                                          \
    {                                                                         \
        ushort_t* base_ = (ushort_t*)smem + (P) * 16384;                      \
        _Pragma("unroll")                                                     \
        for (int st = 0; st < 2; ++st) {                                      \
            const int r_ = st * 64 + r_ld;                                    \
            const size_t eoff_ = (size_t)(b0 + r_) * D_DIM + (KT) + c_ld * 8; \
            const size_t aoff_ = (size_t)(s0 + r_) * D_DIM + (KT) + c_ld * 8; \
            const int ldo_ = st * 2048 + lds_lin;                             \
            gload16(Eh + eoff_, base_ + ldo_);                                \
            gload16(El + eoff_, base_ + 4096 + ldo_);                         \
            gload16(Aht + aoff_, base_ + 8192 + ldo_);                        \
            gload16(Alt + aoff_, base_ + 12288 + ldo_);                       \
        }                                                                     \
    }

    STAGE(0, 0);
    __syncthreads();                 // buf0 ready

#pragma unroll 2
    for (int it = 0; it < 64; ++it) {
        const int cur = it & 1;
        // issue next tile's staging first — latency hides under MFMA below.
        // Writes buf[cur^1], whose previous readers all passed the barrier
        // at the end of iteration it-1, and which is drained by the barrier
        // at the end of THIS iteration before iteration it+1 reads it.
        if (it + 1 < 64) STAGE(cur ^ 1, (it + 1) * 32);

        ushort_t* base = (ushort_t*)smem + cur * 16384;
        short8_t ah[4], al[4], bh[4], bl[4];
#pragma unroll
        for (int mt = 0; mt < 4; ++mt) {
            int row = wm + mt * 16 + (lane & 15);
            ah[mt] = *(const short8_t*)&base[row * 32 + kc];
            al[mt] = *(const short8_t*)&base[4096 + row * 32 + kc];
        }
#pragma unroll
        for (int nt = 0; nt < 4; ++nt) {
            int row = wn + nt * 16 + (lane & 15);
            bh[nt] = *(const short8_t*)&base[8192 + row * 32 + kc];
            bl[nt] = *(const short8_t*)&base[12288 + row * 32 + kc];
        }
#pragma unroll
        for (int mt = 0; mt < 4; ++mt)
#pragma unroll
            for (int nt = 0; nt < 4; ++nt) {
                acc[mt][nt] = __builtin_amdgcn_mfma_f32_16x16x32_bf16(ah[mt], bh[nt], acc[mt][nt], 0, 0, 0);
                acc[mt][nt] = __builtin_amdgcn_mfma_f32_16x16x32_bf16(ah[mt], bl[nt], acc[mt][nt], 0, 0, 0);
                acc[mt][nt] = __builtin_amdgcn_mfma_f32_16x16x32_bf16(al[mt], bh[nt], acc[mt][nt], 0, 0, 0);
            }
        __syncthreads();             // one barrier per K-step
    }
#undef STAGE

    // ---- CF epilogue on acc registers ----
    // C layout (16x16x32): col = lane&15, row = (lane>>4)*4 + reg.
    // Lane's 4 values per tile share one s column.
    const float DT = T_MAX / (float)(KNOTS - 1);

#pragma unroll
    for (int nt = 0; nt < 4; ++nt) {
        float re[KNOTS - 1], im[KNOTS - 1];
#pragma unroll
        for (int k = 0; k < KNOTS - 1; ++k) { re[k] = 0.f; im[k] = 0.f; }
#pragma unroll
        for (int mt = 0; mt < 4; ++mt) {
            f32x4 v = acc[mt][nt];
#pragma unroll
            for (int r = 0; r < 4; ++r) {
                float p = v[r];
                float sn, cs;
                __sincosf(p * DT, &sn, &cs);
                float c = cs, s = sn;
                re[0] += c; im[0] += s;
#pragma unroll
                for (int k = 1; k < KNOTS - 1; ++k) {
                    float cn = fmaf(c, cs, -s * sn);
                    s = fmaf(s, cs, c * sn);
                    c = cn;
                    re[k] += c; im[k] += s;
                }
            }
        }
#pragma unroll
        for (int k = 0; k < KNOTS - 1; ++k) {
            re[k] += __shfl_xor(re[k], 16);
            re[k] += __shfl_xor(re[k], 32);
            im[k] += __shfl_xor(im[k], 16);
            im[k] += __shfl_xor(im[k], 32);
        }
        if (lane < 16) {
            const int sig = nt * 16 + lane;
            float* dst = &cf[(size_t)((((wid & 1) * 2 + (wid >> 1)) * 64 + sig)) * 38];
#pragma unroll
            for (int k = 0; k < KNOTS - 1; ++k) {
                dst[2 * k]     = re[k];
                dst[2 * k + 1] = im[k];
            }
        }
    }
    __syncthreads();

    // combine the two m-parity waves; coalesced partials write
#pragma unroll
    for (int i = 0; i < KNOTS - 1; ++i) {
        const int kc2 = i * 2 + (tid >> 7);   // 0..37
        const int sl = tid & 127;
        const int g = sl >> 6, si = sl & 63;
        float v = cf[(size_t)(((0 * 2 + g) * 64 + si)) * 38 + kc2]
                + cf[(size_t)(((1 * 2 + g) * 64 + si)) * 38 + kc2];
        const int k = kc2 >> 1, c = kc2 & 1;
        partials[((size_t)(bchunk * (KNOTS - 1) + k) * 2 + c) * S_DIM + s0 + sl] = v;
    }
}

// ===========================================================================
// Kernel 4: finalize.
// ===========================================================================
template <int NCH>
__global__ __launch_bounds__(256) void kfinal(const float* __restrict__ partials,
                                              const float* __restrict__ phi,
                                              const float* __restrict__ wts,
                                              float* __restrict__ out) {
    const int idx = blockIdx.x * 256 + threadIdx.x;
    const int kk = idx >> 11;
    const int s = idx & (S_DIM - 1);
    const float invB = 1.0f / (float)B_DIM;

    float re = 0.f, im = 0.f;
    for (int ch = 0; ch < NCH; ++ch) {
        re += partials[(size_t)((ch * (KNOTS - 1) + kk) * 2 + 0) * S_DIM + s];
        im += partials[(size_t)((ch * (KNOTS - 1) + kk) * 2 + 1) * S_DIM + s];
    }
    re = re * invB - phi[kk + 1];
    im *= invB;
    float local = wts[kk + 1] * fmaf(re, re, im * im);

    __shared__ float sred[256];
    sred[threadIdx.x] = local;
    __syncthreads();
    for (int off = 128; off > 0; off >>= 1) {
        if (threadIdx.x < off) sred[threadIdx.x] += sred[threadIdx.x + off];
        __syncthreads();
    }
    if (threadIdx.x == 0) {
        const float scale = (float)D_DIM / (float)S_DIM;
        atomicAdd(out, sred[0] * scale);
    }
}

// ===========================================================================
// Fallback (validated round-2 fp32 path) for small ws_size
// ===========================================================================
#define BM 64
#define BN 64
#define BK 16
#define BTILES 2
#define NCHUNK_F (B_DIM / (BM * BTILES))

template <bool ATOMIC>
__global__ __launch_bounds__(256, 2) void kfused_f32(const float* __restrict__ E,
                                                     const float* __restrict__ A,
                                                     const float* __restrict__ norm2,
                                                     float* __restrict__ partials) {
    const int sblk = blockIdx.x;
    const int bchunk = blockIdx.y;
    const int s0 = sblk * BN;
    const int tid = threadIdx.x;
    const int tx = tid & 15, ty = tid >> 4;
    const int j = tid & 63, g = tid >> 6;

    __shared__ float As[BK][BM + 4];
    __shared__ float Bs[BK][BN + 4];
    __shared__ float Pj[BM][BN + 4];

    const float invn = rsqrtf(norm2[s0 + j]);
    const float DTSTEP = T_MAX / (float)(KNOTS - 1);

    float accRe[KNOTS - 1], accIm[KNOTS - 1];
#pragma unroll
    for (int k = 0; k < KNOTS - 1; ++k) { accRe[k] = 0.f; accIm[k] = 0.f; }

    const int lrow = tid >> 2, lq = tid & 3;
    const int brow = tid >> 4, bq = tid & 15;

    for (int bt = 0; bt < BTILES; ++bt) {
        const int b0 = (bchunk * BTILES + bt) * BM;
        float acc[4][4];
#pragma unroll
        for (int i = 0; i < 4; ++i)
#pragma unroll
            for (int jj = 0; jj < 4; ++jj) acc[i][jj] = 0.f;

        float4 ev = *(const float4*)&E[(size_t)(b0 + lrow) * D_DIM + 0 + lq * 4];
        float4 av = *(const float4*)&A[(size_t)(0 + brow) * S_DIM + s0 + bq * 4];

        for (int kt = 0; kt < D_DIM; kt += BK) {
            __syncthreads();
            As[lq * 4 + 0][lrow] = ev.x;
            As[lq * 4 + 1][lrow] = ev.y;
            As[lq * 4 + 2][lrow] = ev.z;
            As[lq * 4 + 3][lrow] = ev.w;
            *(float4*)&Bs[brow][bq * 4] = av;
            __syncthreads();
            if (kt + BK < D_DIM) {
                ev = *(const float4*)&E[(size_t)(b0 + lrow) * D_DIM + (kt + BK) + lq * 4];
                av = *(const float4*)&A[(size_t)(kt + BK + brow) * S_DIM + s0 + bq * 4];
            }
#pragma unroll
            for (int kk = 0; kk < BK; ++kk) {
                float4 a = *(const float4*)&As[kk][ty * 4];
                float4 b = *(const float4*)&Bs[kk][tx * 4];
                acc[0][0] = fmaf(a.x, b.x, acc[0][0]);
                acc[0][1] = fmaf(a.x, b.y, acc[0][1]);
                acc[0][2] = fmaf(a.x, b.z, acc[0][2]);
                acc[0][3] = fmaf(a.x, b.w, acc[0][3]);
                acc[1][0] = fmaf(a.y, b.x, acc[1][0]);
                acc[1][1] = fmaf(a.y, b.y, acc[1][1]);
                acc[1][2] = fmaf(a.y, b.z, acc[1][2]);
                acc[1][3] = fmaf(a.y, b.w, acc[1][3]);
                acc[2][0] = fmaf(a.z, b.x, acc[2][0]);
                acc[2][1] = fmaf(a.z, b.y, acc[2][1]);
                acc[2][2] = fmaf(a.z, b.z, acc[2][2]);
                acc[2][3] = fmaf(a.z, b.w, acc[2][3]);
                acc[3][0] = fmaf(a.w, b.x, acc[3][0]);
                acc[3][1] = fmaf(a.w, b.y, acc[3][1]);
                acc[3][2] = fmaf(a.w, b.z, acc[3][2]);
                acc[3][3] = fmaf(a.w, b.w, acc[3][3]);
            }
        }
        __syncthreads();
#pragma unroll
        for (int i = 0; i < 4; ++i)
            *(float4*)&Pj[ty * 4 + i][tx * 4] =
                make_float4(acc[i][0], acc[i][1], acc[i][2], acc[i][3]);
        __syncthreads();

#pragma unroll 2
        for (int bl = g * 16; bl < g * 16 + 16; ++bl) {
            float p = Pj[bl][j] * invn;
            float sn, cs;
            __sincosf(p * DTSTEP, &sn, &cs);
            float c = cs, s = sn;
            accRe[0] += c; accIm[0] += s;
#pragma unroll
            for (int kk = 1; kk < KNOTS - 1; ++kk) {
                float cn = fmaf(c, cs, -s * sn);
                s = fmaf(s, cs, c * sn);
                c = cn;
                accRe[kk] += c; accIm[kk] += s;
            }
        }
    }

    __syncthreads();
    float* red = &Pj[0][0];
    if (g == 0) {
#pragma unroll
        for (int kk = 0; kk < KNOTS - 1; ++kk) {
            red[(kk * 2 + 0) * 64 + j] = accRe[kk];
            red[(kk * 2 + 1) * 64 + j] = accIm[kk];
        }
    }
    __syncthreads();
    for (int gg = 1; gg < 4; ++gg) {
        if (g == gg) {
#pragma unroll
            for (int kk = 0; kk < KNOTS - 1; ++kk) {
                red[(kk * 2 + 0) * 64 + j] += accRe[kk];
                red[(kk * 2 + 1) * 64 + j] += accIm[kk];
            }
        }
        __syncthreads();
    }

    if (tid < 64) {
        for (int kk = 0; kk < KNOTS - 1; ++kk) {
            for (int c = 0; c < 2; ++c) {
                const int row = ATOMIC ? kk : (bchunk * (KNOTS - 1) + kk);
                float* dst = &partials[(size_t)(row * 2 + c) * S_DIM + s0 + tid];
                const float v = red[(kk * 2 + c) * 64 + tid];
                if (ATOMIC) atomicAdd(dst, v);
                else        *dst = v;
            }
        }
    }
}

// ===========================================================================
extern "C" void kernel_launch(void* const* d_in, const int* in_sizes, int n_in,
                              void* d_out, int out_size, void* d_ws, size_t ws_size,
                              hipStream_t stream) {
    const float* E   = (const float*)d_in[0];
    const float* A   = (const float*)d_in[1];
    const float* phi = (const float*)d_in[3];
    const float* wts = (const float*)d_in[4];
    float* out = (float*)d_out;

    float* ws_f = (float*)d_ws;
    float* norm2 = ws_f;                          // 2048 floats
    float* partials = ws_f + S_DIM;               // 32*19*2*2048 floats

    const size_t part_elems = (size_t)32 * (KNOTS - 1) * 2 * S_DIM;
    ushort_t* Ehp  = (ushort_t*)(ws_f + S_DIM + part_elems);
    ushort_t* Elp  = Ehp + (size_t)B_DIM * D_DIM;
    ushort_t* Ahtp = Elp + (size_t)B_DIM * D_DIM;
    ushort_t* Altp = Ahtp + (size_t)S_DIM * D_DIM;

    const size_t need_bytes = (S_DIM + part_elems) * sizeof(float)
                            + (2 * (size_t)B_DIM * D_DIM + 2 * (size_t)S_DIM * D_DIM) * sizeof(ushort_t);

    hipMemsetAsync(norm2, 0, S_DIM * sizeof(float), stream);
    hipMemsetAsync(out, 0, sizeof(float), stream);

    knorm<<<dim3(S_DIM / 64, D_DIM / 256), 256, 0, stream>>>(A, norm2);

    if (ws_size >= need_bytes) {
        kconvE<<<dim3((unsigned)((size_t)B_DIM * D_DIM / 8 / 256)), 256, 0, stream>>>(E, Ehp, Elp);
        kconvA<<<dim3(D_DIM / 64, S_DIM / 64), 256, 0, stream>>>(A, norm2, Ahtp, Altp);
        kmain<<<dim3(S_DIM / 128, B_DIM / 128), 256, 0, stream>>>(Ehp, Elp, Ahtp, Altp, partials);
        kfinal<32><<<dim3((KNOTS - 1) * S_DIM / 256), 256, 0, stream>>>(partials, phi, wts, out);
    } else if (ws_size >= (S_DIM + part_elems) * sizeof(float)) {
        kfused_f32<false><<<dim3(S_DIM / BN, NCHUNK_F), 256, 0, stream>>>(E, A, norm2, partials);
        kfinal<NCHUNK_F><<<dim3((KNOTS - 1) * S_DIM / 256), 256, 0, stream>>>(partials, phi, wts, out);
    } else {
        hipMemsetAsync(partials, 0, (size_t)(KNOTS - 1) * 2 * S_DIM * sizeof(float), stream);
        kfused_f32<true><<<dim3(S_DIM / BN, NCHUNK_F), 256, 0, stream>>>(E, A, norm2, partials);
        kfinal<1><<<dim3((KNOTS - 1) * S_DIM / 256), 256, 0, stream>>>(partials, phi, wts, out);
    }
}